// Round 5
// baseline (92.643 us; speedup 1.0000x reference)
//
#include <hip/hip_runtime.h>

#define NPTS    6144
#define DIM     32
#define NB      2
#define NCELL   1000          // 10x10x10, cell edge = 0.03 = radius
#define R2      0.0009f
#define NWAVES  4
#define BLOCK   (NWAVES * 64)
#define LEAFBIT 8192
#define PPT     6             // points per thread in build_cells (6144/1024)
#define NBCAP   128           // max neighbors kept per point (obs ~13)

__device__ __forceinline__ int cellof(float x) {
    int c = (int)(x * (10.0f / 0.3f));
    return min(max(c, 0), 9);
}

// ---- ws layout (ints) ----
#define WS_LEAF   0
#define WS_CSTART 4
#define WS_SORTED 2008   // float4 [NB][NPTS], byte 8032 (16B aligned)

// K1: one block per batch. LDS histogram -> shfl scan -> LDS-cursor scatter.
__global__ __launch_bounds__(1024)
void build_cells(const float* __restrict__ points, const int* __restrict__ leaf,
                 int* __restrict__ ws)
{
    __shared__ int s_hist[1024];
    __shared__ int s_cursor[1024];
    __shared__ int s_wsum[16];
    __shared__ int s_leaf;

    const int t = threadIdx.x;
    const int b = blockIdx.x;
    const int w = t >> 6, lane = t & 63;

    s_hist[t] = 0;
    if (t == 0) s_leaf = 0;

    float px[PPT], py[PPT], pz[PPT];
    int   pc[PPT], pw[PPT];

    __syncthreads();

    int lc = 0;
    #pragma unroll
    for (int r = 0; r < PPT; ++r) {
        const int i  = r * 1024 + t;
        const int gi = b * NPTS + i;
        px[r] = points[gi * 3 + 0];
        py[r] = points[gi * 3 + 1];
        pz[r] = points[gi * 3 + 2];
        const int lf = leaf[gi] > 0 ? 1 : 0;
        lc += lf;
        pc[r] = (cellof(pz[r]) * 10 + cellof(py[r])) * 10 + cellof(px[r]);
        pw[r] = i + (lf ? LEAFBIT : 0);
        atomicAdd(&s_hist[pc[r]], 1);
    }
    #pragma unroll
    for (int off = 32; off > 0; off >>= 1) lc += __shfl_down(lc, off);
    if (lane == 0) atomicAdd(&s_leaf, lc);
    __syncthreads();

    const int v = s_hist[t];
    int x = v;
    #pragma unroll
    for (int off = 1; off < 64; off <<= 1) {
        const int y = __shfl_up(x, off);
        if (lane >= off) x += y;
    }
    if (lane == 63) s_wsum[w] = x;
    __syncthreads();
    if (t < 16) {
        int wv = s_wsum[t];
        #pragma unroll
        for (int off = 1; off < 16; off <<= 1) {
            const int y = __shfl_up(wv, off);
            if (t >= off) wv += y;
        }
        s_wsum[t] = wv;
    }
    __syncthreads();
    const int incl = x + (w > 0 ? s_wsum[w - 1] : 0);
    s_cursor[t] = incl - v;

    if (t < NCELL) ws[WS_CSTART + b * (NCELL + 1) + t + 1] = incl;
    if (t == 0) {
        ws[WS_CSTART + b * (NCELL + 1)] = 0;
        ws[WS_LEAF + b] = s_leaf;
    }
    __syncthreads();

    float4* sorted = (float4*)(ws + WS_SORTED) + (size_t)b * NPTS;
    #pragma unroll
    for (int r = 0; r < PPT; ++r) {
        const int pos = atomicAdd(&s_cursor[pc[r]], 1);
        sorted[pos] = make_float4(px[r], py[r], pz[r], (float)pw[r]);
    }
}

// K2: wave per point. Phase A: concatenated 9-run candidate scan, compact nb
// hits. Phase B: lane-per-hit cosine, survivors listed via ballot-prefix, then
// cooperative 32-lane sum (no atomics). Epilogue MLP reads LDS-staged weights.
__global__ __launch_bounds__(BLOCK)
void refine(const float* __restrict__ emb,
            const float* __restrict__ W1, const float* __restrict__ b1,
            const float* __restrict__ W2, const float* __restrict__ b2,
            const int* __restrict__ ws, float* __restrict__ out)
{
    __shared__ __align__(16) float s_ei[NWAVES][DIM];
    __shared__ float s_mean[NWAVES][DIM];
    __shared__ float s_h[NWAVES][DIM];
    __shared__ int   s_nb[NWAVES][NBCAP];
    __shared__ int   s_sv[NWAVES][NBCAP];
    __shared__ __align__(16) float s_W1[2 * DIM * DIM];
    __shared__ __align__(16) float s_W2[DIM * DIM];
    __shared__ float s_b1[DIM], s_b2[DIM];

    const int tid  = threadIdx.x;
    const int wid  = tid >> 6;
    const int lane = tid & 63;
    const int s    = blockIdx.x * NWAVES + wid;
    const int b    = s / NPTS;
    const int slot = s - b * NPTS;

    const float4* srt  = (const float4*)(ws + WS_SORTED) + (size_t)b * NPTS;
    const int*    cst  = ws + WS_CSTART + b * (NCELL + 1);
    const float*  embB = emb + (size_t)b * NPTS * DIM;

    // stage MLP weights once per block (coalesced float4)
    {
        const float4* w1v = (const float4*)W1;
        float4*       sw1 = (float4*)s_W1;
        for (int idx = tid; idx < (2 * DIM * DIM) / 4; idx += BLOCK) sw1[idx] = w1v[idx];
        const float4* w2v = (const float4*)W2;
        float4*       sw2 = (float4*)s_W2;
        for (int idx = tid; idx < (DIM * DIM) / 4; idx += BLOCK) sw2[idx] = w2v[idx];
        if (tid < DIM) { s_b1[tid] = b1[tid]; s_b2[tid] = b2[tid]; }
    }

    const float4 P  = srt[slot];
    const int    iw = (int)P.w;
    const int    io = iw & (LEAFBIT - 1);
    const bool   li = (iw & LEAFBIT) != 0;
    const bool   ok = ws[WS_LEAF + b] >= 10;      // hoisted scalar load

    if (lane < DIM) s_ei[wid][lane] = embB[(size_t)io * DIM + lane];

    __syncthreads();   // weights + s_ei staged

    float ni2 = 0.0f;
    #pragma unroll
    for (int d = 0; d < DIM; ++d) { const float v = s_ei[wid][d]; ni2 += v * v; }
    const float rni = 1.0f / fmaxf(sqrtf(ni2), 1e-8f);

    const int cx = cellof(P.x), cy = cellof(P.y), cz = cellof(P.z);

    int begv = 0, lenv = 0;
    if (lane < 9) {
        const int z = cz + lane / 3 - 1;
        const int y = cy + lane % 3 - 1;
        if ((unsigned)z <= 9u && (unsigned)y <= 9u) {
            const int rowb = (z * 10 + y) * 10;
            const int c0   = rowb + max(cx - 1, 0);
            const int c1   = rowb + min(cx + 1, 9);
            begv = cst[c0];
            lenv = cst[c1 + 1] - begv;
        }
    }
    const int rb0 = __shfl(begv, 0), rb1 = __shfl(begv, 1), rb2 = __shfl(begv, 2);
    const int rb3 = __shfl(begv, 3), rb4 = __shfl(begv, 4), rb5 = __shfl(begv, 5);
    const int rb6 = __shfl(begv, 6), rb7 = __shfl(begv, 7), rb8 = __shfl(begv, 8);
    const int ln0 = __shfl(lenv, 0), ln1 = __shfl(lenv, 1), ln2 = __shfl(lenv, 2);
    const int ln3 = __shfl(lenv, 3), ln4 = __shfl(lenv, 4), ln5 = __shfl(lenv, 5);
    const int ln6 = __shfl(lenv, 6), ln7 = __shfl(lenv, 7), ln8 = __shfl(lenv, 8);
    const int pf1 = ln0,       pf2 = pf1 + ln1, pf3 = pf2 + ln2;
    const int pf4 = pf3 + ln3, pf5 = pf4 + ln4, pf6 = pf5 + ln5;
    const int pf7 = pf6 + ln6, pf8 = pf7 + ln7, pf9 = pf8 + ln8;

    // ---- Phase A ----
    int nbcnt = 0;
    for (int base = 0; base < pf9; base += 64) {
        const int g = base + lane;
        int j = 0;
        if (g < pf9) j = rb8 + g - pf8;
        if (g < pf8) j = rb7 + g - pf7;
        if (g < pf7) j = rb6 + g - pf6;
        if (g < pf6) j = rb5 + g - pf5;
        if (g < pf5) j = rb4 + g - pf4;
        if (g < pf4) j = rb3 + g - pf3;
        if (g < pf3) j = rb2 + g - pf2;
        if (g < pf2) j = rb1 + g - pf1;
        if (g < pf1) j = rb0 + g;
        const float4 Q  = srt[j];
        const float dx = Q.x - P.x, dy = Q.y - P.y, dz = Q.z - P.z;
        const float d2 = dx * dx + dy * dy + dz * dz;
        const int   jw = (int)Q.w;
        const bool  nb = (g < pf9) && (d2 < R2) && ((jw & LEAFBIT) != 0);
        const unsigned long long m = __ballot(nb);
        if (nb) {
            const int pos = nbcnt + __popcll(m & ((1ull << lane) - 1ull));
            if (pos < NBCAP) s_nb[wid][pos] = jw & (LEAFBIT - 1);
        }
        nbcnt += __popcll(m);
    }
    const int cnt_nb = nbcnt;

    // ---- Phase B: cosine per hit; survivors -> s_sv via ballot prefix ----
    int csim = 0;
    const int nh = min(cnt_nb, NBCAP);
    for (int h0 = 0; h0 < nh; h0 += 64) {
        const int h = h0 + lane;
        bool surv = false;
        int  jo   = 0;
        if (h < nh) {
            jo = s_nb[wid][h];
            const float4* ej4 = (const float4*)(embB + (size_t)jo * DIM);
            float dot = 0.0f, nj2 = 0.0f;
            #pragma unroll
            for (int k = 0; k < DIM / 4; ++k) {
                const float4 v = ej4[k];
                const float4 a = *(const float4*)&s_ei[wid][4 * k];
                dot += a.x * v.x + a.y * v.y + a.z * v.z + a.w * v.w;
                nj2 += v.x * v.x + v.y * v.y + v.z * v.z + v.w * v.w;
            }
            const float rnj = 1.0f / fmaxf(sqrtf(nj2), 1e-8f);
            surv = (dot * rni * rnj) > 0.7f;
        }
        const unsigned long long m = __ballot(surv);
        if (surv) {
            const int pos = csim + __popcll(m & ((1ull << lane) - 1ull));
            s_sv[wid][pos] = jo;
        }
        csim += __popcll(m);
    }

    // cooperative mean over survivors (coalesced, no atomics)
    if (lane < DIM) {
        float msum = 0.0f;
        for (int v = 0; v < csim; ++v)
            msum += embB[(size_t)s_sv[wid][v] * DIM + lane];
        s_mean[wid][lane] = (csim > 0) ? msum / (float)csim : 0.0f;
    }

    const bool cond = ok && li && (cnt_nb > 1) && (csim > 0);   // wave-uniform

    float* outp = out + ((size_t)b * NPTS + io) * DIM;
    if (lane < DIM) {
        if (!cond) {
            outp[lane] = s_ei[wid][lane];
        } else {
            float a0 = s_b1[lane], a1 = 0.0f;
            #pragma unroll
            for (int k = 0; k < DIM; k += 2) {
                a0 = fmaf(s_ei[wid][k],     s_W1[k * DIM + lane],       a0);
                a1 = fmaf(s_ei[wid][k + 1], s_W1[(k + 1) * DIM + lane], a1);
            }
            #pragma unroll
            for (int k = 0; k < DIM; k += 2) {
                a0 = fmaf(s_mean[wid][k],     s_W1[(DIM + k) * DIM + lane],     a0);
                a1 = fmaf(s_mean[wid][k + 1], s_W1[(DIM + k + 1) * DIM + lane], a1);
            }
            s_h[wid][lane] = fmaxf(a0 + a1, 0.0f);
            float c0 = s_b2[lane], c1 = 0.0f;
            #pragma unroll
            for (int k = 0; k < DIM; k += 2) {
                c0 = fmaf(s_h[wid][k],     s_W2[k * DIM + lane],       c0);
                c1 = fmaf(s_h[wid][k + 1], s_W2[(k + 1) * DIM + lane], c1);
            }
            outp[lane] = c0 + c1;
        }
    }
}

extern "C" void kernel_launch(void* const* d_in, const int* in_sizes, int n_in,
                              void* d_out, int out_size, void* d_ws, size_t ws_size,
                              hipStream_t stream) {
    const float* points = (const float*)d_in[0];
    const float* emb    = (const float*)d_in[1];
    const int*   leaf   = (const int*)d_in[2];
    const float* W1     = (const float*)d_in[3];
    const float* b1     = (const float*)d_in[4];
    const float* W2     = (const float*)d_in[5];
    const float* b2     = (const float*)d_in[6];
    float*       outp   = (float*)d_out;
    int*         ws     = (int*)d_ws;

    build_cells<<<NB, 1024, 0, stream>>>(points, leaf, ws);

    const int grid = (NB * NPTS) / NWAVES;                       // 3072
    refine<<<grid, BLOCK, 0, stream>>>(emb, W1, b1, W2, b2, ws, outp);
}

// Round 6
// 88.525 us; speedup vs baseline: 1.0465x; 1.0465x over previous
//
#include <hip/hip_runtime.h>

#define NPTS    6144
#define DIM     32
#define NB      2
#define NCELL   1000          // 10x10x10, cell edge = 0.03 = radius
#define R2      0.0009f
#define NWAVES  4
#define BLOCK   (NWAVES * 64)
#define LEAFBIT 8192
#define PPT     6             // points per thread in build_cells (6144/1024)
#define NBCAP   128           // max neighbors kept per point (obs ~13)

__device__ __forceinline__ int cellof(float x) {
    int c = (int)(x * (10.0f / 0.3f));
    return min(max(c, 0), 9);
}

// ---- ws layout (ints) ----
#define WS_LEAF   0
#define WS_CSTART 4
#define WS_SORTED 2008   // float4 [NB][NPTS], byte 8032 (16B aligned)

// K1: one block per batch. LDS histogram -> shfl scan -> LDS-cursor scatter.
__global__ __launch_bounds__(1024)
void build_cells(const float* __restrict__ points, const int* __restrict__ leaf,
                 int* __restrict__ ws)
{
    __shared__ int s_hist[1024];
    __shared__ int s_cursor[1024];
    __shared__ int s_wsum[16];
    __shared__ int s_leaf;

    const int t = threadIdx.x;
    const int b = blockIdx.x;
    const int w = t >> 6, lane = t & 63;

    s_hist[t] = 0;
    if (t == 0) s_leaf = 0;

    float px[PPT], py[PPT], pz[PPT];
    int   pc[PPT], pw[PPT];

    __syncthreads();

    int lc = 0;
    #pragma unroll
    for (int r = 0; r < PPT; ++r) {
        const int i  = r * 1024 + t;
        const int gi = b * NPTS + i;
        px[r] = points[gi * 3 + 0];
        py[r] = points[gi * 3 + 1];
        pz[r] = points[gi * 3 + 2];
        const int lf = leaf[gi] > 0 ? 1 : 0;
        lc += lf;
        pc[r] = (cellof(pz[r]) * 10 + cellof(py[r])) * 10 + cellof(px[r]);
        pw[r] = i + (lf ? LEAFBIT : 0);
        atomicAdd(&s_hist[pc[r]], 1);
    }
    #pragma unroll
    for (int off = 32; off > 0; off >>= 1) lc += __shfl_down(lc, off);
    if (lane == 0) atomicAdd(&s_leaf, lc);
    __syncthreads();

    const int v = s_hist[t];
    int x = v;
    #pragma unroll
    for (int off = 1; off < 64; off <<= 1) {
        const int y = __shfl_up(x, off);
        if (lane >= off) x += y;
    }
    if (lane == 63) s_wsum[w] = x;
    __syncthreads();
    if (t < 16) {
        int wv = s_wsum[t];
        #pragma unroll
        for (int off = 1; off < 16; off <<= 1) {
            const int y = __shfl_up(wv, off);
            if (t >= off) wv += y;
        }
        s_wsum[t] = wv;
    }
    __syncthreads();
    const int incl = x + (w > 0 ? s_wsum[w - 1] : 0);
    s_cursor[t] = incl - v;

    if (t < NCELL) ws[WS_CSTART + b * (NCELL + 1) + t + 1] = incl;
    if (t == 0) {
        ws[WS_CSTART + b * (NCELL + 1)] = 0;
        ws[WS_LEAF + b] = s_leaf;
    }
    __syncthreads();

    float4* sorted = (float4*)(ws + WS_SORTED) + (size_t)b * NPTS;
    #pragma unroll
    for (int r = 0; r < PPT; ++r) {
        const int pos = atomicAdd(&s_cursor[pc[r]], 1);
        sorted[pos] = make_float4(px[r], py[r], pz[r], (float)pw[r]);
    }
}

// K2: wave per point. Non-leaf (or invalid-batch) waves exit immediately with
// a float4 copy — cond can only hold for leaf points, so ~50% of waves skip
// the scan entirely. Leaf waves: concatenated 9-run scan -> compact hits ->
// lane-per-hit cosine -> atomic-free survivor mean -> MLP (direct L2 weight
// reads; no barriers anywhere in this kernel).
__global__ __launch_bounds__(BLOCK)
void refine(const float* __restrict__ emb,
            const float* __restrict__ W1, const float* __restrict__ b1,
            const float* __restrict__ W2, const float* __restrict__ b2,
            const int* __restrict__ ws, float* __restrict__ out)
{
    __shared__ __align__(16) float s_ei[NWAVES][DIM];
    __shared__ float s_mean[NWAVES][DIM];
    __shared__ float s_h[NWAVES][DIM];
    __shared__ int   s_nb[NWAVES][NBCAP];
    __shared__ int   s_sv[NWAVES][NBCAP];

    const int tid  = threadIdx.x;
    const int wid  = tid >> 6;
    const int lane = tid & 63;
    const int s    = blockIdx.x * NWAVES + wid;
    const int b    = s / NPTS;
    const int slot = s - b * NPTS;

    const float4* srt  = (const float4*)(ws + WS_SORTED) + (size_t)b * NPTS;
    const int*    cst  = ws + WS_CSTART + b * (NCELL + 1);
    const float*  embB = emb + (size_t)b * NPTS * DIM;

    const float4 P  = srt[slot];
    const int    iw = (int)P.w;
    const int    io = iw & (LEAFBIT - 1);
    const bool   li = (iw & LEAFBIT) != 0;
    const bool   ok = ws[WS_LEAF + b] >= 10;

    const float4* e4   = (const float4*)(embB + (size_t)io * DIM);
    float4*       out4 = (float4*)(out + ((size_t)b * NPTS + io) * DIM);

    // ---- early exit: cond requires ok && li; everything else is a copy ----
    if (!(ok && li)) {                   // wave-uniform
        if (lane < DIM / 4) out4[lane] = e4[lane];
        return;
    }

    if (lane < DIM) s_ei[wid][lane] = ((const float*)e4)[lane];

    float ni2 = 0.0f;
    #pragma unroll
    for (int d = 0; d < DIM; ++d) { const float v = s_ei[wid][d]; ni2 += v * v; }
    const float rni = 1.0f / fmaxf(sqrtf(ni2), 1e-8f);

    const int cx = cellof(P.x), cy = cellof(P.y), cz = cellof(P.z);

    int begv = 0, lenv = 0;
    if (lane < 9) {
        const int z = cz + lane / 3 - 1;
        const int y = cy + lane % 3 - 1;
        if ((unsigned)z <= 9u && (unsigned)y <= 9u) {
            const int rowb = (z * 10 + y) * 10;
            const int c0   = rowb + max(cx - 1, 0);
            const int c1   = rowb + min(cx + 1, 9);
            begv = cst[c0];
            lenv = cst[c1 + 1] - begv;
        }
    }
    const int rb0 = __shfl(begv, 0), rb1 = __shfl(begv, 1), rb2 = __shfl(begv, 2);
    const int rb3 = __shfl(begv, 3), rb4 = __shfl(begv, 4), rb5 = __shfl(begv, 5);
    const int rb6 = __shfl(begv, 6), rb7 = __shfl(begv, 7), rb8 = __shfl(begv, 8);
    const int ln0 = __shfl(lenv, 0), ln1 = __shfl(lenv, 1), ln2 = __shfl(lenv, 2);
    const int ln3 = __shfl(lenv, 3), ln4 = __shfl(lenv, 4), ln5 = __shfl(lenv, 5);
    const int ln6 = __shfl(lenv, 6), ln7 = __shfl(lenv, 7), ln8 = __shfl(lenv, 8);
    const int pf1 = ln0,       pf2 = pf1 + ln1, pf3 = pf2 + ln2;
    const int pf4 = pf3 + ln3, pf5 = pf4 + ln4, pf6 = pf5 + ln5;
    const int pf7 = pf6 + ln6, pf8 = pf7 + ln7, pf9 = pf8 + ln8;

    // ---- Phase A: scan candidates, compact nb hits into s_nb ----
    int nbcnt = 0;
    for (int base = 0; base < pf9; base += 64) {
        const int g = base + lane;
        int j = 0;
        if (g < pf9) j = rb8 + g - pf8;
        if (g < pf8) j = rb7 + g - pf7;
        if (g < pf7) j = rb6 + g - pf6;
        if (g < pf6) j = rb5 + g - pf5;
        if (g < pf5) j = rb4 + g - pf4;
        if (g < pf4) j = rb3 + g - pf3;
        if (g < pf3) j = rb2 + g - pf2;
        if (g < pf2) j = rb1 + g - pf1;
        if (g < pf1) j = rb0 + g;
        const float4 Q  = srt[j];
        const float dx = Q.x - P.x, dy = Q.y - P.y, dz = Q.z - P.z;
        const float d2 = dx * dx + dy * dy + dz * dz;
        const int   jw = (int)Q.w;
        const bool  nb = (g < pf9) && (d2 < R2) && ((jw & LEAFBIT) != 0);
        const unsigned long long m = __ballot(nb);
        if (nb) {
            const int pos = nbcnt + __popcll(m & ((1ull << lane) - 1ull));
            if (pos < NBCAP) s_nb[wid][pos] = jw & (LEAFBIT - 1);
        }
        nbcnt += __popcll(m);
    }
    const int cnt_nb = nbcnt;

    // ---- Phase B: cosine per hit; survivors -> s_sv via ballot prefix ----
    int csim = 0;
    const int nh = min(cnt_nb, NBCAP);
    for (int h0 = 0; h0 < nh; h0 += 64) {
        const int h = h0 + lane;
        bool surv = false;
        int  jo   = 0;
        if (h < nh) {
            jo = s_nb[wid][h];
            const float4* ej4 = (const float4*)(embB + (size_t)jo * DIM);
            float dot = 0.0f, nj2 = 0.0f;
            #pragma unroll
            for (int k = 0; k < DIM / 4; ++k) {
                const float4 v = ej4[k];
                const float4 a = *(const float4*)&s_ei[wid][4 * k];
                dot += a.x * v.x + a.y * v.y + a.z * v.z + a.w * v.w;
                nj2 += v.x * v.x + v.y * v.y + v.z * v.z + v.w * v.w;
            }
            const float rnj = 1.0f / fmaxf(sqrtf(nj2), 1e-8f);
            surv = (dot * rni * rnj) > 0.7f;
        }
        const unsigned long long m = __ballot(surv);
        if (surv) {
            const int pos = csim + __popcll(m & ((1ull << lane) - 1ull));
            s_sv[wid][pos] = jo;
        }
        csim += __popcll(m);
    }

    const bool cond = (cnt_nb > 1) && (csim > 0);   // wave-uniform (ok&&li held)

    if (lane < DIM) {
        if (!cond) {
            out[((size_t)b * NPTS + io) * DIM + lane] = s_ei[wid][lane];
        } else {
            // atomic-free survivor mean (coalesced per-survivor rows)
            float msum = 0.0f;
            for (int v = 0; v < csim; ++v)
                msum += embB[(size_t)s_sv[wid][v] * DIM + lane];
            s_mean[wid][lane] = msum / (float)csim;

            float a0 = b1[lane], a1 = 0.0f;
            #pragma unroll
            for (int k = 0; k < DIM; k += 2) {
                a0 = fmaf(s_ei[wid][k],     W1[k * DIM + lane],       a0);
                a1 = fmaf(s_ei[wid][k + 1], W1[(k + 1) * DIM + lane], a1);
            }
            #pragma unroll
            for (int k = 0; k < DIM; k += 2) {
                a0 = fmaf(s_mean[wid][k],     W1[(DIM + k) * DIM + lane],     a0);
                a1 = fmaf(s_mean[wid][k + 1], W1[(DIM + k + 1) * DIM + lane], a1);
            }
            s_h[wid][lane] = fmaxf(a0 + a1, 0.0f);
            float c0 = b2[lane], c1 = 0.0f;
            #pragma unroll
            for (int k = 0; k < DIM; k += 2) {
                c0 = fmaf(s_h[wid][k],     W2[k * DIM + lane],       c0);
                c1 = fmaf(s_h[wid][k + 1], W2[(k + 1) * DIM + lane], c1);
            }
            out[((size_t)b * NPTS + io) * DIM + lane] = c0 + c1;
        }
    }
}

extern "C" void kernel_launch(void* const* d_in, const int* in_sizes, int n_in,
                              void* d_out, int out_size, void* d_ws, size_t ws_size,
                              hipStream_t stream) {
    const float* points = (const float*)d_in[0];
    const float* emb    = (const float*)d_in[1];
    const int*   leaf   = (const int*)d_in[2];
    const float* W1     = (const float*)d_in[3];
    const float* b1     = (const float*)d_in[4];
    const float* W2     = (const float*)d_in[5];
    const float* b2     = (const float*)d_in[6];
    float*       outp   = (float*)d_out;
    int*         ws     = (int*)d_ws;

    build_cells<<<NB, 1024, 0, stream>>>(points, leaf, ws);

    const int grid = (NB * NPTS) / NWAVES;                       // 3072
    refine<<<grid, BLOCK, 0, stream>>>(emb, W1, b1, W2, b2, ws, outp);
}